// Round 1
// baseline (697.079 us; speedup 1.0000x reference)
//
#include <hip/hip_runtime.h>

#define NB 8192
#define ND 256
#define NCLS 64        // affordance ids are in [0,36); allocate 64 for safety
#define LOSS_MARGIN 0.2f
#define NEG_INF_F (-1e9f)

// ---- monotonic float<->uint encoding for atomicMax on floats ----
__device__ __forceinline__ unsigned f2u_mono(float f) {
  unsigned b = __float_as_uint(f);
  return (b & 0x80000000u) ? ~b : (b | 0x80000000u);
}
__device__ __forceinline__ float u2f_mono(unsigned u) {
  return (u & 0x80000000u) ? __uint_as_float(u & 0x7fffffffu)
                           : __uint_as_float(~u);
}

// ---- init workspace ----
__global__ __launch_bounds__(256) void init_kernel(unsigned* __restrict__ hn_enc,
                                                   int* __restrict__ class_count,
                                                   int* __restrict__ class_fill) {
  int i = blockIdx.x * 256 + threadIdx.x;
  if (i < NB) hn_enc[i] = f2u_mono(NEG_INF_F);
  if (i < NCLS) { class_count[i] = 0; class_fill[i] = 0; }
}

// ---- histogram of affordance classes ----
__global__ __launch_bounds__(256) void hist_kernel(const int* __restrict__ aff,
                                                   int* __restrict__ class_count) {
  int i = blockIdx.x * 256 + threadIdx.x;
  atomicAdd(&class_count[aff[i]], 1);
}

// ---- exclusive prefix sum over 64 classes (trivial) ----
__global__ void scan_kernel(const int* __restrict__ class_count,
                            int* __restrict__ class_start) {
  if (threadIdx.x == 0) {
    int s = 0;
    for (int c = 0; c < NCLS; ++c) { class_start[c] = s; s += class_count[c]; }
    class_start[NCLS] = s;
  }
}

// ---- scatter row indices into class-sorted list ----
__global__ __launch_bounds__(256) void scatter_kernel(const int* __restrict__ aff,
                                                      const int* __restrict__ class_start,
                                                      int* __restrict__ class_fill,
                                                      int* __restrict__ class_idx) {
  int i = blockIdx.x * 256 + threadIdx.x;
  int c = aff[i];
  int pos = atomicAdd(&class_fill[c], 1);
  class_idx[class_start[c] + pos] = i;
}

// ---- big kernel: tiled fp32 matmul, fused masked row-max over negatives ----
// Tile 128x128, K-chunks of 64, 256 threads, 8x8 micro-tile per thread.
#define TM 128
#define TN 128
#define TK 64
#define PAD 4

__global__ __launch_bounds__(256) void simmax_kernel(const float* __restrict__ P,
                                                     const int* __restrict__ aff,
                                                     unsigned* __restrict__ hn_enc) {
  __shared__ float As[TK][TM + PAD];  // k-major
  __shared__ float Bs[TK][TN + PAD];
  __shared__ int affI[TM];
  __shared__ int affJ[TN];

  const int t = threadIdx.x;
  const int r0 = blockIdx.x * TM;
  const int c0 = blockIdx.y * TN;
  const int ty = t >> 4;   // 0..15 -> row group (8 rows)
  const int tx = t & 15;   // 0..15 -> col group (8 cols)

  if (t < TM) affI[t] = aff[r0 + t];
  else affJ[t - TM] = aff[c0 + (t - TM)];

  float acc[8][8];
#pragma unroll
  for (int m = 0; m < 8; ++m)
#pragma unroll
    for (int n = 0; n < 8; ++n) acc[m][n] = 0.0f;

#pragma unroll 1
  for (int kc = 0; kc < ND; kc += TK) {
    __syncthreads();  // protect LDS from previous iteration readers
#pragma unroll
    for (int p = 0; p < 8; ++p) {
      const int row = (t >> 4) + (p << 4);        // 0..127
      const int kk = (t & 15) << 2;               // 0..60 step 4
      const float4 va = *reinterpret_cast<const float4*>(
          P + (size_t)(r0 + row) * ND + kc + kk);
      As[kk + 0][row] = va.x; As[kk + 1][row] = va.y;
      As[kk + 2][row] = va.z; As[kk + 3][row] = va.w;
      const float4 vb = *reinterpret_cast<const float4*>(
          P + (size_t)(c0 + row) * ND + kc + kk);
      Bs[kk + 0][row] = vb.x; Bs[kk + 1][row] = vb.y;
      Bs[kk + 2][row] = vb.z; Bs[kk + 3][row] = vb.w;
    }
    __syncthreads();

#pragma unroll 4
    for (int k = 0; k < TK; ++k) {
      float a[8], b[8];
      *reinterpret_cast<float4*>(&a[0]) =
          *reinterpret_cast<const float4*>(&As[k][ty * 8]);
      *reinterpret_cast<float4*>(&a[4]) =
          *reinterpret_cast<const float4*>(&As[k][ty * 8 + 4]);
      *reinterpret_cast<float4*>(&b[0]) =
          *reinterpret_cast<const float4*>(&Bs[k][tx * 8]);
      *reinterpret_cast<float4*>(&b[4]) =
          *reinterpret_cast<const float4*>(&Bs[k][tx * 8 + 4]);
#pragma unroll
      for (int m = 0; m < 8; ++m)
#pragma unroll
        for (int n = 0; n < 8; ++n)
          acc[m][n] = fmaf(a[m], b[n], acc[m][n]);
    }
  }

  // masked row-max over this tile's columns (negatives only: aff differs)
#pragma unroll
  for (int m = 0; m < 8; ++m) {
    const int ai = affI[ty * 8 + m];
    float rmax = NEG_INF_F;
#pragma unroll
    for (int n = 0; n < 8; ++n) {
      if (affJ[tx * 8 + n] != ai) rmax = fmaxf(rmax, acc[m][n]);
    }
    // reduce across the 16 threads (same ty) that share this row.
    // lanes with the same ty are contiguous 16-lane groups within a wave.
    rmax = fmaxf(rmax, __shfl_xor(rmax, 1));
    rmax = fmaxf(rmax, __shfl_xor(rmax, 2));
    rmax = fmaxf(rmax, __shfl_xor(rmax, 4));
    rmax = fmaxf(rmax, __shfl_xor(rmax, 8));
    if (tx == 0) atomicMax(&hn_enc[r0 + ty * 8 + m], f2u_mono(rmax));
  }
}

// ---- loss over positive pairs (within-class), per-row block ----
__global__ __launch_bounds__(256) void loss_kernel(const float* __restrict__ P,
                                                   const int* __restrict__ aff,
                                                   const int* __restrict__ inst,
                                                   const unsigned* __restrict__ hn_enc,
                                                   const int* __restrict__ class_count,
                                                   const int* __restrict__ class_start,
                                                   const int* __restrict__ class_idx,
                                                   float* __restrict__ bsum,
                                                   int* __restrict__ bcnt) {
  const int i = blockIdx.x;
  const int t = threadIdx.x;
  const int c = aff[i];
  const int cnt = class_count[c];

  __shared__ float pi[ND];
  pi[t] = P[(size_t)i * ND + t];
  __syncthreads();

  float lsum = 0.0f;
  int lcnt = 0;

  if (cnt < NB) {  // row has >=1 negative -> potentially valid
    const float hn = u2f_mono(hn_enc[i]);
    const int my_inst = inst[i];
    const int base = class_start[c];
    for (int jj = t; jj < cnt; jj += 256) {
      const int j = class_idx[base + jj];
      if (inst[j] != my_inst) {
        const float4* pj = reinterpret_cast<const float4*>(P + (size_t)j * ND);
        float dot = 0.0f;
#pragma unroll 8
        for (int d4 = 0; d4 < ND / 4; ++d4) {
          const float4 v = pj[d4];
          const float4 u = *reinterpret_cast<const float4*>(&pi[d4 * 4]);
          dot = fmaf(v.x, u.x, dot);
          dot = fmaf(v.y, u.y, dot);
          dot = fmaf(v.z, u.z, dot);
          dot = fmaf(v.w, u.w, dot);
        }
        lsum += fmaxf(hn - dot + LOSS_MARGIN, 0.0f);
        lcnt += 1;
      }
    }
  }

  // block reduce (wave shfl + LDS across 4 waves)
  for (int off = 32; off; off >>= 1) {
    lsum += __shfl_down(lsum, off);
    lcnt += __shfl_down(lcnt, off);
  }
  __shared__ float wsum[4];
  __shared__ int wcnt[4];
  if ((t & 63) == 0) { wsum[t >> 6] = lsum; wcnt[t >> 6] = lcnt; }
  __syncthreads();
  if (t == 0) {
    bsum[i] = wsum[0] + wsum[1] + wsum[2] + wsum[3];
    bcnt[i] = wcnt[0] + wcnt[1] + wcnt[2] + wcnt[3];
  }
}

// ---- final deterministic reduction -> scalar ----
__global__ __launch_bounds__(256) void finalize_kernel(const float* __restrict__ bsum,
                                                       const int* __restrict__ bcnt,
                                                       float* __restrict__ out) {
  const int t = threadIdx.x;
  float s = 0.0f;
  int n = 0;
  for (int i = t; i < NB; i += 256) { s += bsum[i]; n += bcnt[i]; }
  for (int off = 32; off; off >>= 1) {
    s += __shfl_down(s, off);
    n += __shfl_down(n, off);
  }
  __shared__ float wsum[4];
  __shared__ int wcnt[4];
  if ((t & 63) == 0) { wsum[t >> 6] = s; wcnt[t >> 6] = n; }
  __syncthreads();
  if (t == 0) {
    const float S = wsum[0] + wsum[1] + wsum[2] + wsum[3];
    const int N = wcnt[0] + wcnt[1] + wcnt[2] + wcnt[3];
    out[0] = (N > 0) ? (S / (float)N) : 0.0f;
  }
}

extern "C" void kernel_launch(void* const* d_in, const int* in_sizes, int n_in,
                              void* d_out, int out_size, void* d_ws, size_t ws_size,
                              hipStream_t stream) {
  const float* P = (const float*)d_in[0];
  const int* aff = (const int*)d_in[1];
  const int* inst = (const int*)d_in[2];
  float* out = (float*)d_out;

  // workspace layout (all 4-byte ints/floats)
  int* base = (int*)d_ws;
  unsigned* hn_enc = (unsigned*)base;                 // NB
  int* class_count = base + NB;                       // NCLS
  int* class_start = base + NB + NCLS;                // NCLS+1
  int* class_fill  = base + NB + NCLS + NCLS + 1;     // NCLS
  int* class_idx   = base + NB + 3 * NCLS + 1;        // NB
  float* bsum = (float*)(base + 2 * NB + 3 * NCLS + 1);  // NB
  int* bcnt   = base + 3 * NB + 3 * NCLS + 1;            // NB

  init_kernel<<<NB / 256, 256, 0, stream>>>(hn_enc, class_count, class_fill);
  hist_kernel<<<NB / 256, 256, 0, stream>>>(aff, class_count);
  scan_kernel<<<1, 64, 0, stream>>>(class_count, class_start);
  scatter_kernel<<<NB / 256, 256, 0, stream>>>(aff, class_start, class_fill, class_idx);
  simmax_kernel<<<dim3(NB / TM, NB / TN), 256, 0, stream>>>(P, aff, hn_enc);
  loss_kernel<<<NB, 256, 0, stream>>>(P, aff, inst, hn_enc, class_count,
                                      class_start, class_idx, bsum, bcnt);
  finalize_kernel<<<1, 256, 0, stream>>>(bsum, bcnt, out);
}

// Round 2
// 144.536 us; speedup vs baseline: 4.8229x; 4.8229x over previous
//
#include <hip/hip_runtime.h>

#define NB 8192
#define ND 256
#define NCLS 64
#define LOSS_MARGIN 0.2f
#define NEG_INF_F (-1e9f)
#define LMAXT 3                      // supports class sizes up to 384 (actual ~228±15)
#define NBLK_LOSS (NCLS * LMAXT * LMAXT)

typedef __attribute__((ext_vector_type(8))) __bf16 bf16x8;
typedef __attribute__((ext_vector_type(4))) float f32x4;

// ---- monotonic float<->uint encoding for atomicMax on floats ----
__device__ __forceinline__ unsigned f2u_mono(float f) {
  unsigned b = __float_as_uint(f);
  return (b & 0x80000000u) ? ~b : (b | 0x80000000u);
}
__device__ __forceinline__ float u2f_mono(unsigned u) {
  return (u & 0x80000000u) ? __uint_as_float(u & 0x7fffffffu)
                           : __uint_as_float(~u);
}

// fp32 -> bf16 bits, round-to-nearest-even
__device__ __forceinline__ unsigned short f2bf(float f) {
  unsigned u = __float_as_uint(f);
  unsigned r = (u + 0x7fffu + ((u >> 16) & 1u)) >> 16;
  return (unsigned short)r;
}

// async global->LDS, 16 bytes per lane (LDS dest: wave-uniform base + lane*16)
__device__ __forceinline__ void gl_lds16(const void* gsrc, void* ldst) {
  __builtin_amdgcn_global_load_lds(
      (const __attribute__((address_space(1))) void*)gsrc,
      (__attribute__((address_space(3))) void*)ldst, 16, 0, 0);
}

// ---- zero class_count ----
__global__ __launch_bounds__(256) void init_small(int* __restrict__ class_count) {
  if (threadIdx.x < NCLS) class_count[threadIdx.x] = 0;
}

// ---- histogram (order-independent -> deterministic) ----
__global__ __launch_bounds__(256) void hist_kernel(const int* __restrict__ aff,
                                                   int* __restrict__ class_count) {
  int i = blockIdx.x * 256 + threadIdx.x;
  atomicAdd(&class_count[aff[i]], 1);
}

// ---- exclusive scan over 64 classes ----
__global__ void scan_kernel(const int* __restrict__ class_count,
                            int* __restrict__ class_start) {
  if (threadIdx.x == 0) {
    int s = 0;
    for (int c = 0; c < NCLS; ++c) { class_start[c] = s; s += class_count[c]; }
    class_start[NCLS] = s;
  }
}

// ---- deterministic ordered class index build (one block per class) ----
__global__ __launch_bounds__(256) void build_idx(const int* __restrict__ aff,
                                                 const int* __restrict__ class_start,
                                                 int* __restrict__ class_idx) {
  const int c = blockIdx.x;
  const int base = class_start[c];
  const int t = threadIdx.x;
  const int lane = t & 63, wave = t >> 6;
  __shared__ int wtot[4];
  __shared__ int s_off;
  if (t == 0) s_off = 0;
  __syncthreads();
  for (int pass = 0; pass < NB / 256; ++pass) {
    int i = pass * 256 + t;
    bool m = (aff[i] == c);
    unsigned long long mask = __ballot(m);
    if (lane == 0) wtot[wave] = __popcll(mask);
    __syncthreads();
    int off = s_off;
    int prefix = 0;
    for (int w = 0; w < wave; ++w) prefix += wtot[w];
    int lanepre = __popcll(mask & ((1ull << lane) - 1ull));
    if (m) class_idx[base + off + prefix + lanepre] = i;
    __syncthreads();
    if (t == 0) s_off = off + wtot[0] + wtot[1] + wtot[2] + wtot[3];
    __syncthreads();
  }
}

// ---- gather rows in class order, convert to bf16; init per-row state ----
__global__ __launch_bounds__(256) void gather_convert(const float* __restrict__ P,
                                                      const int* __restrict__ aff,
                                                      const int* __restrict__ inst,
                                                      const int* __restrict__ class_idx,
                                                      unsigned short* __restrict__ Psort,
                                                      int* __restrict__ affSort,
                                                      int* __restrict__ instSort,
                                                      unsigned* __restrict__ hn_enc) {
  const int t = threadIdx.x;
  const int sr = blockIdx.x * 8 + (t >> 5);
  const int c = t & 31;
  const int src = class_idx[sr];
  const float4* ps = (const float4*)(P + (size_t)src * ND);
  ushort4* pd = (ushort4*)(Psort + (size_t)sr * ND);
#pragma unroll
  for (int q = 0; q < 2; ++q) {
    float4 v = ps[c + q * 32];
    ushort4 h;
    h.x = f2bf(v.x); h.y = f2bf(v.y); h.z = f2bf(v.z); h.w = f2bf(v.w);
    pd[c + q * 32] = h;
  }
  if (c == 0) {
    affSort[sr] = aff[src];
    instSort[sr] = inst[src];
    hn_enc[sr] = f2u_mono(NEG_INF_F);
  }
}

// ---- MFMA simmax: C = Psort * Psort^T tile (bi<=bj), masked row/col max ----
// 128x128 tile, BK=32, 4 waves each 64x64 (4x4 frags of 16x16x32).
// LDS chunk layout: chunk(kg,row) at offset (kg*128+row)*16B -> conflict-free frag reads.
__global__ __launch_bounds__(256, 2) void simmax_mfma(const unsigned short* __restrict__ Psort,
                                                      const int* __restrict__ affSort,
                                                      unsigned* __restrict__ hn_enc) {
  const int bi = blockIdx.x, bj = blockIdx.y;
  if (bj < bi) return;
  __shared__ __align__(16) unsigned short At[4096];  // 8 KB
  __shared__ __align__(16) unsigned short Bt[4096];
  __shared__ int affI[128], affJ[128];

  const int t = threadIdx.x;
  const int lane = t & 63;
  const int wave = t >> 6;
  const int r0 = bi * 128, c0 = bj * 128;

  if (t < 128) affI[t] = affSort[r0 + t];
  else affJ[t - 128] = affSort[c0 + (t - 128)];

  const int wr = (wave >> 1) * 64;
  const int wc = (wave & 1) * 64;

  f32x4 acc[4][4];
#pragma unroll
  for (int m = 0; m < 4; ++m)
#pragma unroll
    for (int n = 0; n < 4; ++n) acc[m][n] = (f32x4){0.f, 0.f, 0.f, 0.f};

  const int ci0 = t, ci1 = 256 + t;
  const int kg0 = ci0 >> 7, rw0 = ci0 & 127;
  const int kg1 = ci1 >> 7, rw1 = ci1 & 127;

#pragma unroll 1
  for (int kc = 0; kc < ND; kc += 32) {
    __syncthreads();
    gl_lds16(Psort + (size_t)(r0 + rw0) * ND + kc + kg0 * 8, &At[ci0 * 8]);
    gl_lds16(Psort + (size_t)(c0 + rw0) * ND + kc + kg0 * 8, &Bt[ci0 * 8]);
    gl_lds16(Psort + (size_t)(r0 + rw1) * ND + kc + kg1 * 8, &At[ci1 * 8]);
    gl_lds16(Psort + (size_t)(c0 + rw1) * ND + kc + kg1 * 8, &Bt[ci1 * 8]);
    __syncthreads();

    const int kg = lane >> 4, lr = lane & 15;
    bf16x8 a[4], b[4];
#pragma unroll
    for (int m = 0; m < 4; ++m)
      a[m] = *(const bf16x8*)&At[(kg * 128 + wr + m * 16 + lr) * 8];
#pragma unroll
    for (int n = 0; n < 4; ++n)
      b[n] = *(const bf16x8*)&Bt[(kg * 128 + wc + n * 16 + lr) * 8];
#pragma unroll
    for (int m = 0; m < 4; ++m)
#pragma unroll
      for (int n = 0; n < 4; ++n)
        acc[m][n] = __builtin_amdgcn_mfma_f32_16x16x32_bf16(a[m], b[n], acc[m][n], 0, 0, 0);
  }

  // row-max over negatives (aff differs); C/D layout: col=lane&15, row=(lane>>4)*4+reg
#pragma unroll
  for (int m = 0; m < 4; ++m) {
#pragma unroll
    for (int r = 0; r < 4; ++r) {
      const int lrow = wr + m * 16 + (lane >> 4) * 4 + r;
      const int ai = affI[lrow];
      float rmax = NEG_INF_F;
#pragma unroll
      for (int n = 0; n < 4; ++n) {
        const int lcol = wc + n * 16 + (lane & 15);
        if (affJ[lcol] != ai) rmax = fmaxf(rmax, acc[m][n][r]);
      }
      rmax = fmaxf(rmax, __shfl_xor(rmax, 1));
      rmax = fmaxf(rmax, __shfl_xor(rmax, 2));
      rmax = fmaxf(rmax, __shfl_xor(rmax, 4));
      rmax = fmaxf(rmax, __shfl_xor(rmax, 8));
      if ((lane & 15) == 0) atomicMax(&hn_enc[r0 + lrow], f2u_mono(rmax));
    }
  }
  if (bi != bj) {
    // col-max: column j of this tile = row j of the transposed (uncomputed) tile
#pragma unroll
    for (int n = 0; n < 4; ++n) {
      const int lcol = wc + n * 16 + (lane & 15);
      const int aj = affJ[lcol];
      float cmax = NEG_INF_F;
#pragma unroll
      for (int m = 0; m < 4; ++m) {
        const int lrb = wr + m * 16 + (lane >> 4) * 4;
#pragma unroll
        for (int r = 0; r < 4; ++r)
          if (affI[lrb + r] != aj) cmax = fmaxf(cmax, acc[m][n][r]);
      }
      cmax = fmaxf(cmax, __shfl_xor(cmax, 16));
      cmax = fmaxf(cmax, __shfl_xor(cmax, 32));
      if ((lane >> 4) == 0) atomicMax(&hn_enc[c0 + lcol], f2u_mono(cmax));
    }
  }
}

// ---- loss: within-class Gram tiles + hinge epilogue ----
__global__ __launch_bounds__(256, 2) void loss_mfma(const unsigned short* __restrict__ Psort,
                                                    const int* __restrict__ class_start,
                                                    const int* __restrict__ instSort,
                                                    const unsigned* __restrict__ hn_enc,
                                                    float* __restrict__ bsum,
                                                    int* __restrict__ bcnt) {
  const int c = blockIdx.z;
  const int ti = blockIdx.x, tj = blockIdx.y;
  const int bid = (c * LMAXT + ti) * LMAXT + tj;
  const int t = threadIdx.x;
  const int base = class_start[c];
  const int cnt = class_start[c + 1] - base;
  const int nt = (cnt + 127) >> 7;
  if (ti >= nt || tj >= nt || cnt >= NB) {
    if (t == 0) { bsum[bid] = 0.f; bcnt[bid] = 0; }
    return;
  }

  __shared__ __align__(16) unsigned short At[4096];
  __shared__ __align__(16) unsigned short Bt[4096];
  __shared__ int instI[128], instJ[128];
  __shared__ float hnI[128];

  const int lane = t & 63;
  const int wave = t >> 6;

  if (t < 128) {
    int ri = ti * 128 + t;
    int gi = base + (ri < cnt ? ri : 0);
    instI[t] = instSort[gi];
    hnI[t] = u2f_mono(hn_enc[gi]);
  } else {
    int tt = t - 128;
    int rj = tj * 128 + tt;
    int gj = base + (rj < cnt ? rj : 0);
    instJ[tt] = instSort[gj];
  }

  const int wr = (wave >> 1) * 64;
  const int wc = (wave & 1) * 64;

  f32x4 acc[4][4];
#pragma unroll
  for (int m = 0; m < 4; ++m)
#pragma unroll
    for (int n = 0; n < 4; ++n) acc[m][n] = (f32x4){0.f, 0.f, 0.f, 0.f};

  const int ci0 = t, ci1 = 256 + t;
  const int kg0 = ci0 >> 7, rw0 = ci0 & 127;
  const int kg1 = ci1 >> 7, rw1 = ci1 & 127;
  // clamped source rows (garbage beyond cnt is masked in epilogue)
  const int ra0 = base + (ti * 128 + rw0 < cnt ? ti * 128 + rw0 : 0);
  const int ra1 = base + (ti * 128 + rw1 < cnt ? ti * 128 + rw1 : 0);
  const int rb0 = base + (tj * 128 + rw0 < cnt ? tj * 128 + rw0 : 0);
  const int rb1 = base + (tj * 128 + rw1 < cnt ? tj * 128 + rw1 : 0);

#pragma unroll 1
  for (int kc = 0; kc < ND; kc += 32) {
    __syncthreads();
    gl_lds16(Psort + (size_t)ra0 * ND + kc + kg0 * 8, &At[ci0 * 8]);
    gl_lds16(Psort + (size_t)rb0 * ND + kc + kg0 * 8, &Bt[ci0 * 8]);
    gl_lds16(Psort + (size_t)ra1 * ND + kc + kg1 * 8, &At[ci1 * 8]);
    gl_lds16(Psort + (size_t)rb1 * ND + kc + kg1 * 8, &Bt[ci1 * 8]);
    __syncthreads();

    const int kg = lane >> 4, lr = lane & 15;
    bf16x8 a[4], b[4];
#pragma unroll
    for (int m = 0; m < 4; ++m)
      a[m] = *(const bf16x8*)&At[(kg * 128 + wr + m * 16 + lr) * 8];
#pragma unroll
    for (int n = 0; n < 4; ++n)
      b[n] = *(const bf16x8*)&Bt[(kg * 128 + wc + n * 16 + lr) * 8];
#pragma unroll
    for (int m = 0; m < 4; ++m)
#pragma unroll
      for (int n = 0; n < 4; ++n)
        acc[m][n] = __builtin_amdgcn_mfma_f32_16x16x32_bf16(a[m], b[n], acc[m][n], 0, 0, 0);
  }

  float lsum = 0.f;
  int lcnt = 0;
#pragma unroll
  for (int m = 0; m < 4; ++m) {
#pragma unroll
    for (int r = 0; r < 4; ++r) {
      const int lrow = wr + m * 16 + (lane >> 4) * 4 + r;
      const int ri = ti * 128 + lrow;
      if (ri >= cnt) continue;
      const float hn = hnI[lrow];
      const int ii = instI[lrow];
#pragma unroll
      for (int n = 0; n < 4; ++n) {
        const int lcol = wc + n * 16 + (lane & 15);
        const int rj = tj * 128 + lcol;
        if (rj < cnt && instJ[lcol] != ii) {
          lsum += fmaxf(hn - acc[m][n][r] + LOSS_MARGIN, 0.f);
          lcnt += 1;
        }
      }
    }
  }

  for (int off = 32; off; off >>= 1) {
    lsum += __shfl_down(lsum, off);
    lcnt += __shfl_down(lcnt, off);
  }
  __shared__ float wsum[4];
  __shared__ int wcnt[4];
  if (lane == 0) { wsum[wave] = lsum; wcnt[wave] = lcnt; }
  __syncthreads();
  if (t == 0) {
    bsum[bid] = wsum[0] + wsum[1] + wsum[2] + wsum[3];
    bcnt[bid] = wcnt[0] + wcnt[1] + wcnt[2] + wcnt[3];
  }
}

// ---- final deterministic reduction -> scalar ----
__global__ __launch_bounds__(256) void finalize_kernel(const float* __restrict__ bsum,
                                                       const int* __restrict__ bcnt,
                                                       float* __restrict__ out) {
  const int t = threadIdx.x;
  float s = 0.f;
  int n = 0;
  for (int i = t; i < NBLK_LOSS; i += 256) { s += bsum[i]; n += bcnt[i]; }
  for (int off = 32; off; off >>= 1) {
    s += __shfl_down(s, off);
    n += __shfl_down(n, off);
  }
  __shared__ float wsum[4];
  __shared__ int wcnt[4];
  if ((t & 63) == 0) { wsum[t >> 6] = s; wcnt[t >> 6] = n; }
  __syncthreads();
  if (t == 0) {
    const float S = wsum[0] + wsum[1] + wsum[2] + wsum[3];
    const int N = wcnt[0] + wcnt[1] + wcnt[2] + wcnt[3];
    out[0] = (N > 0) ? (S / (float)N) : 0.0f;
  }
}

extern "C" void kernel_launch(void* const* d_in, const int* in_sizes, int n_in,
                              void* d_out, int out_size, void* d_ws, size_t ws_size,
                              hipStream_t stream) {
  const float* P = (const float*)d_in[0];
  const int* aff = (const int*)d_in[1];
  const int* inst = (const int*)d_in[2];
  float* out = (float*)d_out;

  // workspace layout
  unsigned short* Psort = (unsigned short*)d_ws;          // NB*ND bf16 = 4 MB
  int* ibase = (int*)((char*)d_ws + (size_t)NB * ND * 2);
  unsigned* hn_enc = (unsigned*)ibase;                    // NB
  int* class_count = ibase + NB;                          // NCLS
  int* class_start = ibase + NB + NCLS;                   // NCLS+1
  int* class_idx   = ibase + NB + 2 * NCLS + 1;           // NB
  int* affSort     = ibase + 2 * NB + 2 * NCLS + 1;       // NB
  int* instSort    = ibase + 3 * NB + 2 * NCLS + 1;       // NB
  float* bsum = (float*)(ibase + 4 * NB + 2 * NCLS + 1);  // NBLK_LOSS
  int* bcnt   = ibase + 4 * NB + 2 * NCLS + 1 + NBLK_LOSS;

  init_small<<<1, 256, 0, stream>>>(class_count);
  hist_kernel<<<NB / 256, 256, 0, stream>>>(aff, class_count);
  scan_kernel<<<1, 64, 0, stream>>>(class_count, class_start);
  build_idx<<<NCLS, 256, 0, stream>>>(aff, class_start, class_idx);
  gather_convert<<<NB / 8, 256, 0, stream>>>(P, aff, inst, class_idx, Psort,
                                             affSort, instSort, hn_enc);
  simmax_mfma<<<dim3(64, 64), 256, 0, stream>>>(Psort, affSort, hn_enc);
  loss_mfma<<<dim3(LMAXT, LMAXT, NCLS), 256, 0, stream>>>(Psort, class_start, instSort,
                                                          hn_enc, bsum, bcnt);
  finalize_kernel<<<1, 256, 0, stream>>>(bsum, bcnt, out);
}

// Round 3
// 103.583 us; speedup vs baseline: 6.7296x; 1.3954x over previous
//
#include <hip/hip_runtime.h>

#define NB 8192
#define ND 256
#define NCLS 64
#define LOSS_MARGIN 0.2f
#define NEG_INF_F (-1e9f)
#define LMAXT 3
#define NBLK_LOSS (NCLS * LMAXT * LMAXT)
#define NTILE_T 2080   // 64*65/2 triangular tiles

typedef __attribute__((ext_vector_type(8))) __bf16 bf16x8;
typedef __attribute__((ext_vector_type(4))) float f32x4;

// ---- monotonic float<->uint encoding for atomicMax on floats ----
__device__ __forceinline__ unsigned f2u_mono(float f) {
  unsigned b = __float_as_uint(f);
  return (b & 0x80000000u) ? ~b : (b | 0x80000000u);
}
__device__ __forceinline__ float u2f_mono(unsigned u) {
  return (u & 0x80000000u) ? __uint_as_float(u & 0x7fffffffu)
                           : __uint_as_float(~u);
}

// fp32 -> bf16 bits, round-to-nearest-even
__device__ __forceinline__ unsigned short f2bf(float f) {
  unsigned u = __float_as_uint(f);
  unsigned r = (u + 0x7fffu + ((u >> 16) & 1u)) >> 16;
  return (unsigned short)r;
}

// async global->LDS, 16 bytes per lane
__device__ __forceinline__ void gl_lds16(const void* gsrc, void* ldst) {
  __builtin_amdgcn_global_load_lds(
      (const __attribute__((address_space(1))) void*)gsrc,
      (__attribute__((address_space(3))) void*)ldst, 16, 0, 0);
}

// ---- fused: class_start + deterministic ordered class index list ----
// one block per class, 1024 threads (16 waves). base(c) = #{i : aff[i] < c}.
__global__ __launch_bounds__(1024) void build_idx_fused(const int* __restrict__ aff,
                                                        int* __restrict__ class_start,
                                                        int* __restrict__ class_idx) {
  const int c = blockIdx.x;
  const int t = threadIdx.x;
  const int lane = t & 63, wave = t >> 6;
  __shared__ int wtot[16];
  __shared__ int s_off;

  // pass 1: count aff[i] < c  -> base
  int lt = 0;
  for (int i = t; i < NB; i += 1024) lt += (aff[i] < c) ? 1 : 0;
  for (int off = 32; off; off >>= 1) lt += __shfl_down(lt, off);
  if (lane == 0) wtot[wave] = lt;
  __syncthreads();
  int base = 0;
  for (int w = 0; w < 16; ++w) base += wtot[w];
  if (t == 0) {
    class_start[c] = base;
    if (c == 0) class_start[NCLS] = NB;
  }
  __syncthreads();  // protect wtot reuse
  if (t == 0) s_off = 0;
  __syncthreads();

  // pass 2: stable scatter of indices with aff[i]==c
  for (int pass = 0; pass < NB / 1024; ++pass) {
    const int i = pass * 1024 + t;
    const bool m = (aff[i] == c);
    const unsigned long long mask = __ballot(m);
    if (lane == 0) wtot[wave] = __popcll(mask);
    __syncthreads();
    const int off = s_off;
    int prefix = 0;
    for (int w = 0; w < wave; ++w) prefix += wtot[w];
    if (m)
      class_idx[base + off + prefix +
                __popcll(mask & ((1ull << lane) - 1ull))] = i;
    __syncthreads();
    if (t == 0) {
      int tot = 0;
      for (int w = 0; w < 16; ++w) tot += wtot[w];
      s_off = off + tot;
    }
    __syncthreads();
  }
}

// ---- gather rows in class order, convert to bf16; init per-row state ----
__global__ __launch_bounds__(256) void gather_convert(const float* __restrict__ P,
                                                      const int* __restrict__ aff,
                                                      const int* __restrict__ inst,
                                                      const int* __restrict__ class_idx,
                                                      unsigned short* __restrict__ Psort,
                                                      int* __restrict__ affSort,
                                                      int* __restrict__ instSort,
                                                      unsigned* __restrict__ hn_enc) {
  const int t = threadIdx.x;
  const int sr = blockIdx.x * 8 + (t >> 5);
  const int c = t & 31;
  const int src = class_idx[sr];
  const float4* ps = (const float4*)(P + (size_t)src * ND);
  ushort4* pd = (ushort4*)(Psort + (size_t)sr * ND);
#pragma unroll
  for (int q = 0; q < 2; ++q) {
    float4 v = ps[c + q * 32];
    ushort4 h;
    h.x = f2bf(v.x); h.y = f2bf(v.y); h.z = f2bf(v.z); h.w = f2bf(v.w);
    pd[c + q * 32] = h;
  }
  if (c == 0) {
    affSort[sr] = aff[src];
    instSort[sr] = inst[src];
    hn_enc[sr] = f2u_mono(NEG_INF_F);
  }
}

// ---- MFMA simmax: triangular tiles bi<=bj, 2-phase dbuf pipeline ----
__global__ __launch_bounds__(256, 4) void simmax_mfma(const unsigned short* __restrict__ Psort,
                                                      const int* __restrict__ affSort,
                                                      unsigned* __restrict__ hn_enc) {
  // XCD-aware swizzle (bijective: 2080 % 8 == 0), then triangular decode
  int wg = blockIdx.x;
  wg = (wg & 7) * (NTILE_T / 8) + (wg >> 3);
  int bi = (int)((129.0f - sqrtf(129.0f * 129.0f - 8.0f * (float)wg)) * 0.5f);
  while (bi * 64 - bi * (bi - 1) / 2 > wg) --bi;
  while ((bi + 1) * 64 - (bi + 1) * bi / 2 <= wg) ++bi;
  const int bj = bi + (wg - (bi * 64 - bi * (bi - 1) / 2));

  __shared__ __align__(16) unsigned short At[2][4096];  // 2 x 8 KB
  __shared__ __align__(16) unsigned short Bt[2][4096];
  __shared__ int affI[128], affJ[128];

  const int t = threadIdx.x;
  const int lane = t & 63;
  const int wave = t >> 6;
  const int r0 = bi * 128, c0 = bj * 128;

  if (t < 128) affI[t] = affSort[r0 + t];
  else affJ[t - 128] = affSort[c0 + (t - 128)];

  const int wr = (wave >> 1) * 64;
  const int wc = (wave & 1) * 64;

  f32x4 acc[4][4];
#pragma unroll
  for (int m = 0; m < 4; ++m)
#pragma unroll
    for (int n = 0; n < 4; ++n) acc[m][n] = (f32x4){0.f, 0.f, 0.f, 0.f};

  const int ci0 = t, ci1 = 256 + t;
  const int kg0 = ci0 >> 7, rw0 = ci0 & 127;
  const int kg1 = ci1 >> 7, rw1 = ci1 & 127;

#define STAGE_SIM(B, KC)                                                      \
  do {                                                                        \
    gl_lds16(Psort + (size_t)(r0 + rw0) * ND + (KC) + kg0 * 8, &At[B][ci0 * 8]); \
    gl_lds16(Psort + (size_t)(c0 + rw0) * ND + (KC) + kg0 * 8, &Bt[B][ci0 * 8]); \
    gl_lds16(Psort + (size_t)(r0 + rw1) * ND + (KC) + kg1 * 8, &At[B][ci1 * 8]); \
    gl_lds16(Psort + (size_t)(c0 + rw1) * ND + (KC) + kg1 * 8, &Bt[B][ci1 * 8]); \
  } while (0)

  STAGE_SIM(0, 0);
  asm volatile("s_waitcnt vmcnt(0) lgkmcnt(0)" ::: "memory");
  __builtin_amdgcn_s_barrier();
  __builtin_amdgcn_sched_barrier(0);

  int cur = 0;
#pragma unroll 1
  for (int s = 0; s < 8; ++s) {
    if (s < 7) STAGE_SIM(cur ^ 1, (s + 1) * 32);
    const int kg = lane >> 4, lr = lane & 15;
    bf16x8 a[4], b[4];
#pragma unroll
    for (int m = 0; m < 4; ++m)
      a[m] = *(const bf16x8*)&At[cur][(kg * 128 + wr + m * 16 + lr) * 8];
#pragma unroll
    for (int n = 0; n < 4; ++n)
      b[n] = *(const bf16x8*)&Bt[cur][(kg * 128 + wc + n * 16 + lr) * 8];
#pragma unroll
    for (int m = 0; m < 4; ++m)
#pragma unroll
      for (int n = 0; n < 4; ++n)
        acc[m][n] = __builtin_amdgcn_mfma_f32_16x16x32_bf16(a[m], b[n], acc[m][n], 0, 0, 0);
    __builtin_amdgcn_sched_barrier(0);
    if (s < 7) {
      asm volatile("s_waitcnt vmcnt(0) lgkmcnt(0)" ::: "memory");
      __builtin_amdgcn_s_barrier();
      __builtin_amdgcn_sched_barrier(0);
    }
    cur ^= 1;
  }

  // row-max over negatives; C/D layout: col=lane&15, row=(lane>>4)*4+reg
#pragma unroll
  for (int m = 0; m < 4; ++m) {
#pragma unroll
    for (int r = 0; r < 4; ++r) {
      const int lrow = wr + m * 16 + (lane >> 4) * 4 + r;
      const int ai = affI[lrow];
      float rmax = NEG_INF_F;
#pragma unroll
      for (int n = 0; n < 4; ++n) {
        const int lcol = wc + n * 16 + (lane & 15);
        if (affJ[lcol] != ai) rmax = fmaxf(rmax, acc[m][n][r]);
      }
      rmax = fmaxf(rmax, __shfl_xor(rmax, 1));
      rmax = fmaxf(rmax, __shfl_xor(rmax, 2));
      rmax = fmaxf(rmax, __shfl_xor(rmax, 4));
      rmax = fmaxf(rmax, __shfl_xor(rmax, 8));
      if ((lane & 15) == 0) atomicMax(&hn_enc[r0 + lrow], f2u_mono(rmax));
    }
  }
  if (bi != bj) {
#pragma unroll
    for (int n = 0; n < 4; ++n) {
      const int lcol = wc + n * 16 + (lane & 15);
      const int aj = affJ[lcol];
      float cmax = NEG_INF_F;
#pragma unroll
      for (int m = 0; m < 4; ++m) {
        const int lrb = wr + m * 16 + (lane >> 4) * 4;
#pragma unroll
        for (int r = 0; r < 4; ++r)
          if (affI[lrb + r] != aj) cmax = fmaxf(cmax, acc[m][n][r]);
      }
      cmax = fmaxf(cmax, __shfl_xor(cmax, 16));
      cmax = fmaxf(cmax, __shfl_xor(cmax, 32));
      if ((lane >> 4) == 0) atomicMax(&hn_enc[c0 + lcol], f2u_mono(cmax));
    }
  }
#undef STAGE_SIM
}

// ---- loss: within-class Gram tiles + hinge epilogue (same pipeline) ----
__global__ __launch_bounds__(256, 4) void loss_mfma(const unsigned short* __restrict__ Psort,
                                                    const int* __restrict__ class_start,
                                                    const int* __restrict__ instSort,
                                                    const unsigned* __restrict__ hn_enc,
                                                    float* __restrict__ bsum,
                                                    int* __restrict__ bcnt) {
  const int c = blockIdx.z;
  const int ti = blockIdx.x, tj = blockIdx.y;
  const int bid = (c * LMAXT + ti) * LMAXT + tj;
  const int t = threadIdx.x;
  const int base = class_start[c];
  const int cnt = class_start[c + 1] - base;
  const int nt = (cnt + 127) >> 7;
  if (ti >= nt || tj >= nt || cnt >= NB) {
    if (t == 0) { bsum[bid] = 0.f; bcnt[bid] = 0; }
    return;
  }

  __shared__ __align__(16) unsigned short At[2][4096];
  __shared__ __align__(16) unsigned short Bt[2][4096];
  __shared__ int instI[128], instJ[128];
  __shared__ float hnI[128];

  const int lane = t & 63;
  const int wave = t >> 6;

  if (t < 128) {
    int ri = ti * 128 + t;
    int gi = base + (ri < cnt ? ri : 0);
    instI[t] = instSort[gi];
    hnI[t] = u2f_mono(hn_enc[gi]);
  } else {
    int tt = t - 128;
    int rj = tj * 128 + tt;
    int gj = base + (rj < cnt ? rj : 0);
    instJ[tt] = instSort[gj];
  }

  const int wr = (wave >> 1) * 64;
  const int wc = (wave & 1) * 64;

  f32x4 acc[4][4];
#pragma unroll
  for (int m = 0; m < 4; ++m)
#pragma unroll
    for (int n = 0; n < 4; ++n) acc[m][n] = (f32x4){0.f, 0.f, 0.f, 0.f};

  const int ci0 = t, ci1 = 256 + t;
  const int kg0 = ci0 >> 7, rw0 = ci0 & 127;
  const int kg1 = ci1 >> 7, rw1 = ci1 & 127;
  const int ra0 = base + (ti * 128 + rw0 < cnt ? ti * 128 + rw0 : 0);
  const int ra1 = base + (ti * 128 + rw1 < cnt ? ti * 128 + rw1 : 0);
  const int rb0 = base + (tj * 128 + rw0 < cnt ? tj * 128 + rw0 : 0);
  const int rb1 = base + (tj * 128 + rw1 < cnt ? tj * 128 + rw1 : 0);

#define STAGE_LOSS(B, KC)                                               \
  do {                                                                  \
    gl_lds16(Psort + (size_t)ra0 * ND + (KC) + kg0 * 8, &At[B][ci0 * 8]); \
    gl_lds16(Psort + (size_t)rb0 * ND + (KC) + kg0 * 8, &Bt[B][ci0 * 8]); \
    gl_lds16(Psort + (size_t)ra1 * ND + (KC) + kg1 * 8, &At[B][ci1 * 8]); \
    gl_lds16(Psort + (size_t)rb1 * ND + (KC) + kg1 * 8, &Bt[B][ci1 * 8]); \
  } while (0)

  STAGE_LOSS(0, 0);
  asm volatile("s_waitcnt vmcnt(0) lgkmcnt(0)" ::: "memory");
  __builtin_amdgcn_s_barrier();
  __builtin_amdgcn_sched_barrier(0);

  int cur = 0;
#pragma unroll 1
  for (int s = 0; s < 8; ++s) {
    if (s < 7) STAGE_LOSS(cur ^ 1, (s + 1) * 32);
    const int kg = lane >> 4, lr = lane & 15;
    bf16x8 a[4], b[4];
#pragma unroll
    for (int m = 0; m < 4; ++m)
      a[m] = *(const bf16x8*)&At[cur][(kg * 128 + wr + m * 16 + lr) * 8];
#pragma unroll
    for (int n = 0; n < 4; ++n)
      b[n] = *(const bf16x8*)&Bt[cur][(kg * 128 + wc + n * 16 + lr) * 8];
#pragma unroll
    for (int m = 0; m < 4; ++m)
#pragma unroll
      for (int n = 0; n < 4; ++n)
        acc[m][n] = __builtin_amdgcn_mfma_f32_16x16x32_bf16(a[m], b[n], acc[m][n], 0, 0, 0);
    __builtin_amdgcn_sched_barrier(0);
    if (s < 7) {
      asm volatile("s_waitcnt vmcnt(0) lgkmcnt(0)" ::: "memory");
      __builtin_amdgcn_s_barrier();
      __builtin_amdgcn_sched_barrier(0);
    }
    cur ^= 1;
  }

  float lsum = 0.f;
  int lcnt = 0;
#pragma unroll
  for (int m = 0; m < 4; ++m) {
#pragma unroll
    for (int r = 0; r < 4; ++r) {
      const int lrow = wr + m * 16 + (lane >> 4) * 4 + r;
      const int ri = ti * 128 + lrow;
      if (ri >= cnt) continue;
      const float hn = hnI[lrow];
      const int ii = instI[lrow];
#pragma unroll
      for (int n = 0; n < 4; ++n) {
        const int lcol = wc + n * 16 + (lane & 15);
        const int rj = tj * 128 + lcol;
        if (rj < cnt && instJ[lcol] != ii) {
          lsum += fmaxf(hn - acc[m][n][r] + LOSS_MARGIN, 0.f);
          lcnt += 1;
        }
      }
    }
  }

  for (int off = 32; off; off >>= 1) {
    lsum += __shfl_down(lsum, off);
    lcnt += __shfl_down(lcnt, off);
  }
  __shared__ float wsum[4];
  __shared__ int wcnt[4];
  if (lane == 0) { wsum[wave] = lsum; wcnt[wave] = lcnt; }
  __syncthreads();
  if (t == 0) {
    bsum[bid] = wsum[0] + wsum[1] + wsum[2] + wsum[3];
    bcnt[bid] = wcnt[0] + wcnt[1] + wcnt[2] + wcnt[3];
  }
#undef STAGE_LOSS
}

// ---- final deterministic reduction -> scalar ----
__global__ __launch_bounds__(256) void finalize_kernel(const float* __restrict__ bsum,
                                                       const int* __restrict__ bcnt,
                                                       float* __restrict__ out) {
  const int t = threadIdx.x;
  float s = 0.f;
  int n = 0;
  for (int i = t; i < NBLK_LOSS; i += 256) { s += bsum[i]; n += bcnt[i]; }
  for (int off = 32; off; off >>= 1) {
    s += __shfl_down(s, off);
    n += __shfl_down(n, off);
  }
  __shared__ float wsum[4];
  __shared__ int wcnt[4];
  if ((t & 63) == 0) { wsum[t >> 6] = s; wcnt[t >> 6] = n; }
  __syncthreads();
  if (t == 0) {
    const float S = wsum[0] + wsum[1] + wsum[2] + wsum[3];
    const int N = wcnt[0] + wcnt[1] + wcnt[2] + wcnt[3];
    out[0] = (N > 0) ? (S / (float)N) : 0.0f;
  }
}

extern "C" void kernel_launch(void* const* d_in, const int* in_sizes, int n_in,
                              void* d_out, int out_size, void* d_ws, size_t ws_size,
                              hipStream_t stream) {
  const float* P = (const float*)d_in[0];
  const int* aff = (const int*)d_in[1];
  const int* inst = (const int*)d_in[2];
  float* out = (float*)d_out;

  unsigned short* Psort = (unsigned short*)d_ws;          // NB*ND bf16 = 4 MB
  int* ibase = (int*)((char*)d_ws + (size_t)NB * ND * 2);
  unsigned* hn_enc = (unsigned*)ibase;                    // NB
  int* class_start = ibase + NB;                          // NCLS+1
  int* class_idx   = ibase + NB + NCLS + 1;               // NB
  int* affSort     = ibase + 2 * NB + NCLS + 1;           // NB
  int* instSort    = ibase + 3 * NB + NCLS + 1;           // NB
  float* bsum = (float*)(ibase + 4 * NB + NCLS + 1);      // NBLK_LOSS
  int* bcnt   = ibase + 4 * NB + NCLS + 1 + NBLK_LOSS;    // NBLK_LOSS

  build_idx_fused<<<NCLS, 1024, 0, stream>>>(aff, class_start, class_idx);
  gather_convert<<<NB / 8, 256, 0, stream>>>(P, aff, inst, class_idx, Psort,
                                             affSort, instSort, hn_enc);
  simmax_mfma<<<NTILE_T, 256, 0, stream>>>(Psort, affSort, hn_enc);
  loss_mfma<<<dim3(LMAXT, LMAXT, NCLS), 256, 0, stream>>>(Psort, class_start, instSort,
                                                          hn_enc, bsum, bcnt);
  finalize_kernel<<<1, 256, 0, stream>>>(bsum, bcnt, out);
}

// Round 5
// 90.623 us; speedup vs baseline: 7.6921x; 1.1430x over previous
//
#include <hip/hip_runtime.h>

#define NB 8192
#define ND 256
#define NCLS 64
#define LOSS_MARGIN 0.2f
#define NEG_INF_F (-1e9f)
#define LMAXT 3
#define NBLK_LOSS (NCLS * LMAXT * LMAXT)
#define NTILE_T 2080   // 64*65/2 triangular tiles

typedef __attribute__((ext_vector_type(8))) __bf16 bf16x8;
typedef __attribute__((ext_vector_type(4))) float f32x4;

// fp32 -> bf16 bits, round-to-nearest-even
__device__ __forceinline__ unsigned short f2bf(float f) {
  unsigned u = __float_as_uint(f);
  unsigned r = (u + 0x7fffu + ((u >> 16) & 1u)) >> 16;
  return (unsigned short)r;
}

// async global->LDS, 16 bytes per lane
__device__ __forceinline__ void gl_lds16(const void* gsrc, void* ldst) {
  __builtin_amdgcn_global_load_lds(
      (const __attribute__((address_space(1))) void*)gsrc,
      (__attribute__((address_space(3))) void*)ldst, 16, 0, 0);
}

// ---- fused: class_start + deterministic ordered class index list ----
__global__ __launch_bounds__(1024) void build_idx_fused(const int* __restrict__ aff,
                                                        int* __restrict__ class_start,
                                                        int* __restrict__ class_idx) {
  const int c = blockIdx.x;
  const int t = threadIdx.x;
  const int lane = t & 63, wave = t >> 6;
  __shared__ int wtot[16];
  __shared__ int s_off;

  // pass 1: count aff[i] < c  -> base
  int lt = 0;
  for (int i = t; i < NB; i += 1024) lt += (aff[i] < c) ? 1 : 0;
  for (int off = 32; off; off >>= 1) lt += __shfl_down(lt, off);
  if (lane == 0) wtot[wave] = lt;
  __syncthreads();
  int base = 0;
  for (int w = 0; w < 16; ++w) base += wtot[w];
  if (t == 0) {
    class_start[c] = base;
    if (c == 0) class_start[NCLS] = NB;
  }
  __syncthreads();
  if (t == 0) s_off = 0;
  __syncthreads();

  // pass 2: stable scatter of indices with aff[i]==c
  for (int pass = 0; pass < NB / 1024; ++pass) {
    const int i = pass * 1024 + t;
    const bool m = (aff[i] == c);
    const unsigned long long mask = __ballot(m);
    if (lane == 0) wtot[wave] = __popcll(mask);
    __syncthreads();
    const int off = s_off;
    int prefix = 0;
    for (int w = 0; w < wave; ++w) prefix += wtot[w];
    if (m)
      class_idx[base + off + prefix +
                __popcll(mask & ((1ull << lane) - 1ull))] = i;
    __syncthreads();
    if (t == 0) {
      int tot = 0;
      for (int w = 0; w < 16; ++w) tot += wtot[w];
      s_off = off + tot;
    }
    __syncthreads();
  }
}

// ---- gather rows in class order, convert to bf16 ----
__global__ __launch_bounds__(256) void gather_convert(const float* __restrict__ P,
                                                      const int* __restrict__ aff,
                                                      const int* __restrict__ inst,
                                                      const int* __restrict__ class_idx,
                                                      unsigned short* __restrict__ Psort,
                                                      int* __restrict__ affSort,
                                                      int* __restrict__ instSort) {
  const int t = threadIdx.x;
  const int sr = blockIdx.x * 8 + (t >> 5);
  const int c = t & 31;
  const int src = class_idx[sr];
  const float4* ps = (const float4*)(P + (size_t)src * ND);
  ushort4* pd = (ushort4*)(Psort + (size_t)sr * ND);
#pragma unroll
  for (int q = 0; q < 2; ++q) {
    float4 v = ps[c + q * 32];
    ushort4 h;
    h.x = f2bf(v.x); h.y = f2bf(v.y); h.z = f2bf(v.z); h.w = f2bf(v.w);
    pd[c + q * 32] = h;
  }
  if (c == 0) {
    affSort[sr] = aff[src];
    instSort[sr] = inst[src];
  }
}

// ---- MFMA simmax: triangular tiles bi<=bj, 2-phase dbuf pipeline ----
// Epilogue: per-wave partial maxima combined across the 2 wave-halves in LDS
// (unique writer per slot), then ONE plain store per (row,tile-col) slot:
// row-max -> part[row*64+bj]; off-diagonal also col-max -> part[col*64+bi].
__global__ __launch_bounds__(256, 4) void simmax_mfma(const unsigned short* __restrict__ Psort,
                                                      const int* __restrict__ affSort,
                                                      float* __restrict__ part) {
  int wg = blockIdx.x;
  wg = (wg & 7) * (NTILE_T / 8) + (wg >> 3);
  int bi = (int)((129.0f - sqrtf(129.0f * 129.0f - 8.0f * (float)wg)) * 0.5f);
  while (bi * 64 - bi * (bi - 1) / 2 > wg) --bi;
  while ((bi + 1) * 64 - (bi + 1) * bi / 2 <= wg) ++bi;
  const int bj = bi + (wg - (bi * 64 - bi * (bi - 1) / 2));

  __shared__ __align__(16) unsigned short At[2][4096];
  __shared__ __align__(16) unsigned short Bt[2][4096];
  __shared__ int affI[128], affJ[128];
  __shared__ float rowmax_s[128][2];   // [row][wc-half]
  __shared__ float colmax_s[128][2];   // [col][wr-half]

  const int t = threadIdx.x;
  const int lane = t & 63;
  const int wave = t >> 6;
  const int r0 = bi * 128, c0 = bj * 128;

  if (t < 128) affI[t] = affSort[r0 + t];
  else affJ[t - 128] = affSort[c0 + (t - 128)];

  const int wr = (wave >> 1) * 64;
  const int wc = (wave & 1) * 64;

  f32x4 acc[4][4];
#pragma unroll
  for (int m = 0; m < 4; ++m)
#pragma unroll
    for (int n = 0; n < 4; ++n) acc[m][n] = (f32x4){0.f, 0.f, 0.f, 0.f};

  const int ci0 = t, ci1 = 256 + t;
  const int kg0 = ci0 >> 7, rw0 = ci0 & 127;
  const int kg1 = ci1 >> 7, rw1 = ci1 & 127;

#define STAGE_SIM(B, KC)                                                      \
  do {                                                                        \
    gl_lds16(Psort + (size_t)(r0 + rw0) * ND + (KC) + kg0 * 8, &At[B][ci0 * 8]); \
    gl_lds16(Psort + (size_t)(c0 + rw0) * ND + (KC) + kg0 * 8, &Bt[B][ci0 * 8]); \
    gl_lds16(Psort + (size_t)(r0 + rw1) * ND + (KC) + kg1 * 8, &At[B][ci1 * 8]); \
    gl_lds16(Psort + (size_t)(c0 + rw1) * ND + (KC) + kg1 * 8, &Bt[B][ci1 * 8]); \
  } while (0)

  STAGE_SIM(0, 0);
  asm volatile("s_waitcnt vmcnt(0) lgkmcnt(0)" ::: "memory");
  __builtin_amdgcn_s_barrier();
  __builtin_amdgcn_sched_barrier(0);

  int cur = 0;
#pragma unroll 1
  for (int s = 0; s < 8; ++s) {
    if (s < 7) STAGE_SIM(cur ^ 1, (s + 1) * 32);
    const int kg = lane >> 4, lr = lane & 15;
    bf16x8 a[4], b[4];
#pragma unroll
    for (int m = 0; m < 4; ++m)
      a[m] = *(const bf16x8*)&At[cur][(kg * 128 + wr + m * 16 + lr) * 8];
#pragma unroll
    for (int n = 0; n < 4; ++n)
      b[n] = *(const bf16x8*)&Bt[cur][(kg * 128 + wc + n * 16 + lr) * 8];
#pragma unroll
    for (int m = 0; m < 4; ++m)
#pragma unroll
      for (int n = 0; n < 4; ++n)
        acc[m][n] = __builtin_amdgcn_mfma_f32_16x16x32_bf16(a[m], b[n], acc[m][n], 0, 0, 0);
    __builtin_amdgcn_sched_barrier(0);
    if (s < 7) {
      asm volatile("s_waitcnt vmcnt(0) lgkmcnt(0)" ::: "memory");
      __builtin_amdgcn_s_barrier();
      __builtin_amdgcn_sched_barrier(0);
    }
    cur ^= 1;
  }

  // per-wave row-max over negatives; C/D layout: col=lane&15, row=(lane>>4)*4+reg
#pragma unroll
  for (int m = 0; m < 4; ++m) {
#pragma unroll
    for (int r = 0; r < 4; ++r) {
      const int lrow = wr + m * 16 + (lane >> 4) * 4 + r;
      const int ai = affI[lrow];
      float rmax = NEG_INF_F;
#pragma unroll
      for (int n = 0; n < 4; ++n) {
        const int lcol = wc + n * 16 + (lane & 15);
        if (affJ[lcol] != ai) rmax = fmaxf(rmax, acc[m][n][r]);
      }
      rmax = fmaxf(rmax, __shfl_xor(rmax, 1));
      rmax = fmaxf(rmax, __shfl_xor(rmax, 2));
      rmax = fmaxf(rmax, __shfl_xor(rmax, 4));
      rmax = fmaxf(rmax, __shfl_xor(rmax, 8));
      if ((lane & 15) == 0) rowmax_s[lrow][wc >> 6] = rmax;
    }
  }
  if (bi != bj) {
#pragma unroll
    for (int n = 0; n < 4; ++n) {
      const int lcol = wc + n * 16 + (lane & 15);
      const int aj = affJ[lcol];
      float cmax = NEG_INF_F;
#pragma unroll
      for (int m = 0; m < 4; ++m) {
        const int lrb = wr + m * 16 + (lane >> 4) * 4;
#pragma unroll
        for (int r = 0; r < 4; ++r)
          if (affI[lrb + r] != aj) cmax = fmaxf(cmax, acc[m][n][r]);
      }
      cmax = fmaxf(cmax, __shfl_xor(cmax, 16));
      cmax = fmaxf(cmax, __shfl_xor(cmax, 32));
      if (lane < 16) colmax_s[lcol][wr >> 6] = cmax;
    }
  }
  __syncthreads();
  if (t < 128) {
    part[(size_t)(r0 + t) * 64 + bj] = fmaxf(rowmax_s[t][0], rowmax_s[t][1]);
  } else if (bi != bj) {
    const int c = t - 128;
    part[(size_t)(c0 + c) * 64 + bi] = fmaxf(colmax_s[c][0], colmax_s[c][1]);
  }
#undef STAGE_SIM
}

// ---- reduce 64 partial maxima per row -> hn[row] ----
__global__ __launch_bounds__(256) void hn_reduce(const float* __restrict__ part,
                                                 float* __restrict__ hn) {
  const int i = blockIdx.x * 256 + threadIdx.x;
  const float4* p = (const float4*)(part + (size_t)i * 64);
  float m = NEG_INF_F;
#pragma unroll
  for (int q = 0; q < 16; ++q) {
    float4 v = p[q];
    m = fmaxf(m, fmaxf(fmaxf(v.x, v.y), fmaxf(v.z, v.w)));
  }
  hn[i] = m;
}

// ---- loss: within-class Gram tiles + hinge epilogue ----
__global__ __launch_bounds__(256, 4) void loss_mfma(const unsigned short* __restrict__ Psort,
                                                    const int* __restrict__ class_start,
                                                    const int* __restrict__ instSort,
                                                    const float* __restrict__ hn,
                                                    float* __restrict__ bsum,
                                                    int* __restrict__ bcnt) {
  const int c = blockIdx.z;
  const int ti = blockIdx.x, tj = blockIdx.y;
  const int bid = (c * LMAXT + ti) * LMAXT + tj;
  const int t = threadIdx.x;
  const int base = class_start[c];
  const int cnt = class_start[c + 1] - base;
  const int nt = (cnt + 127) >> 7;
  if (ti >= nt || tj >= nt || cnt >= NB) {
    if (t == 0) { bsum[bid] = 0.f; bcnt[bid] = 0; }
    return;
  }

  __shared__ __align__(16) unsigned short At[2][4096];
  __shared__ __align__(16) unsigned short Bt[2][4096];
  __shared__ int instI[128], instJ[128];
  __shared__ float hnI[128];

  const int lane = t & 63;
  const int wave = t >> 6;

  if (t < 128) {
    int ri = ti * 128 + t;
    int gi = base + (ri < cnt ? ri : 0);
    instI[t] = instSort[gi];
    hnI[t] = hn[gi];
  } else {
    int tt = t - 128;
    int rj = tj * 128 + tt;
    int gj = base + (rj < cnt ? rj : 0);
    instJ[tt] = instSort[gj];
  }

  const int wr = (wave >> 1) * 64;
  const int wc = (wave & 1) * 64;

  f32x4 acc[4][4];
#pragma unroll
  for (int m = 0; m < 4; ++m)
#pragma unroll
    for (int n = 0; n < 4; ++n) acc[m][n] = (f32x4){0.f, 0.f, 0.f, 0.f};

  const int ci0 = t, ci1 = 256 + t;
  const int kg0 = ci0 >> 7, rw0 = ci0 & 127;
  const int kg1 = ci1 >> 7, rw1 = ci1 & 127;
  const int ra0 = base + (ti * 128 + rw0 < cnt ? ti * 128 + rw0 : 0);
  const int ra1 = base + (ti * 128 + rw1 < cnt ? ti * 128 + rw1 : 0);
  const int rb0 = base + (tj * 128 + rw0 < cnt ? tj * 128 + rw0 : 0);
  const int rb1 = base + (tj * 128 + rw1 < cnt ? tj * 128 + rw1 : 0);

#define STAGE_LOSS(B, KC)                                               \
  do {                                                                  \
    gl_lds16(Psort + (size_t)ra0 * ND + (KC) + kg0 * 8, &At[B][ci0 * 8]); \
    gl_lds16(Psort + (size_t)rb0 * ND + (KC) + kg0 * 8, &Bt[B][ci0 * 8]); \
    gl_lds16(Psort + (size_t)ra1 * ND + (KC) + kg1 * 8, &At[B][ci1 * 8]); \
    gl_lds16(Psort + (size_t)rb1 * ND + (KC) + kg1 * 8, &Bt[B][ci1 * 8]); \
  } while (0)

  STAGE_LOSS(0, 0);
  asm volatile("s_waitcnt vmcnt(0) lgkmcnt(0)" ::: "memory");
  __builtin_amdgcn_s_barrier();
  __builtin_amdgcn_sched_barrier(0);

  int cur = 0;
#pragma unroll 1
  for (int s = 0; s < 8; ++s) {
    if (s < 7) STAGE_LOSS(cur ^ 1, (s + 1) * 32);
    const int kg = lane >> 4, lr = lane & 15;
    bf16x8 a[4], b[4];
#pragma unroll
    for (int m = 0; m < 4; ++m)
      a[m] = *(const bf16x8*)&At[cur][(kg * 128 + wr + m * 16 + lr) * 8];
#pragma unroll
    for (int n = 0; n < 4; ++n)
      b[n] = *(const bf16x8*)&Bt[cur][(kg * 128 + wc + n * 16 + lr) * 8];
#pragma unroll
    for (int m = 0; m < 4; ++m)
#pragma unroll
      for (int n = 0; n < 4; ++n)
        acc[m][n] = __builtin_amdgcn_mfma_f32_16x16x32_bf16(a[m], b[n], acc[m][n], 0, 0, 0);
    __builtin_amdgcn_sched_barrier(0);
    if (s < 7) {
      asm volatile("s_waitcnt vmcnt(0) lgkmcnt(0)" ::: "memory");
      __builtin_amdgcn_s_barrier();
      __builtin_amdgcn_sched_barrier(0);
    }
    cur ^= 1;
  }

  float lsum = 0.f;
  int lcnt = 0;
#pragma unroll
  for (int m = 0; m < 4; ++m) {
#pragma unroll
    for (int r = 0; r < 4; ++r) {
      const int lrow = wr + m * 16 + (lane >> 4) * 4 + r;
      const int ri = ti * 128 + lrow;
      if (ri >= cnt) continue;
      const float hnv = hnI[lrow];
      const int ii = instI[lrow];
#pragma unroll
      for (int n = 0; n < 4; ++n) {
        const int lcol = wc + n * 16 + (lane & 15);
        const int rj = tj * 128 + lcol;
        if (rj < cnt && instJ[lcol] != ii) {
          lsum += fmaxf(hnv - acc[m][n][r] + LOSS_MARGIN, 0.f);
          lcnt += 1;
        }
      }
    }
  }

  for (int off = 32; off; off >>= 1) {
    lsum += __shfl_down(lsum, off);
    lcnt += __shfl_down(lcnt, off);
  }
  __shared__ float wsum[4];
  __shared__ int wcnt[4];
  if (lane == 0) { wsum[wave] = lsum; wcnt[wave] = lcnt; }
  __syncthreads();
  if (t == 0) {
    bsum[bid] = wsum[0] + wsum[1] + wsum[2] + wsum[3];
    bcnt[bid] = wcnt[0] + wcnt[1] + wcnt[2] + wcnt[3];
  }
#undef STAGE_LOSS
}

// ---- final deterministic reduction -> scalar ----
__global__ __launch_bounds__(256) void finalize_kernel(const float* __restrict__ bsum,
                                                       const int* __restrict__ bcnt,
                                                       float* __restrict__ out) {
  const int t = threadIdx.x;
  float s = 0.f;
  int n = 0;
  for (int i = t; i < NBLK_LOSS; i += 256) { s += bsum[i]; n += bcnt[i]; }
  for (int off = 32; off; off >>= 1) {
    s += __shfl_down(s, off);
    n += __shfl_down(n, off);
  }
  __shared__ float wsum[4];
  __shared__ int wcnt[4];
  if ((t & 63) == 0) { wsum[t >> 6] = s; wcnt[t >> 6] = n; }
  __syncthreads();
  if (t == 0) {
    const float S = wsum[0] + wsum[1] + wsum[2] + wsum[3];
    const int N = wcnt[0] + wcnt[1] + wcnt[2] + wcnt[3];
    out[0] = (N > 0) ? (S / (float)N) : 0.0f;
  }
}

extern "C" void kernel_launch(void* const* d_in, const int* in_sizes, int n_in,
                              void* d_out, int out_size, void* d_ws, size_t ws_size,
                              hipStream_t stream) {
  const float* P = (const float*)d_in[0];
  const int* aff = (const int*)d_in[1];
  const int* inst = (const int*)d_in[2];
  float* out = (float*)d_out;

  unsigned short* Psort = (unsigned short*)d_ws;            // NB*ND bf16 = 4 MB
  float* part = (float*)((char*)d_ws + (size_t)NB * ND * 2);  // NB*64 f32 = 2 MB
  int* ibase = (int*)((char*)part + (size_t)NB * 64 * 4);
  float* hn        = (float*)ibase;                         // NB
  int* class_start = ibase + NB;                            // NCLS+1
  int* class_idx   = ibase + NB + NCLS + 1;                 // NB
  int* affSort     = ibase + 2 * NB + NCLS + 1;             // NB
  int* instSort    = ibase + 3 * NB + NCLS + 1;             // NB
  float* bsum = (float*)(ibase + 4 * NB + NCLS + 1);        // NBLK_LOSS
  int* bcnt   = ibase + 4 * NB + NCLS + 1 + NBLK_LOSS;      // NBLK_LOSS

  build_idx_fused<<<NCLS, 1024, 0, stream>>>(aff, class_start, class_idx);
  gather_convert<<<NB / 8, 256, 0, stream>>>(P, aff, inst, class_idx, Psort,
                                             affSort, instSort);
  simmax_mfma<<<NTILE_T, 256, 0, stream>>>(Psort, affSort, part);
  hn_reduce<<<NB / 256, 256, 0, stream>>>(part, hn);
  loss_mfma<<<dim3(LMAXT, LMAXT, NCLS), 256, 0, stream>>>(Psort, class_start, instSort,
                                                          hn, bsum, bcnt);
  finalize_kernel<<<1, 256, 0, stream>>>(bsum, bcnt, out);
}